// Round 3
// baseline (17742.027 us; speedup 1.0000x reference)
//
#include <hip/hip_runtime.h>
#include <cstdint>
#include <cstddef>

typedef unsigned short ushort_t;
typedef __attribute__((ext_vector_type(8))) short short8;
typedef __attribute__((ext_vector_type(4))) float floatx4;

#define SS 128
#define BB 64
#define EE 1024
#define HH 1024
#define OO 135
#define WLW 64
#define PLP 32
#define TT 100
#define KP 160    // padded pose K (135 -> 160)
#define KC 2272   // combined K: 1024 (h) + 1024 (esum) + 224 (wsum)
#define NOP 144   // padded pose out dim

static __device__ __forceinline__ float bf2f(ushort_t u) {
    union { unsigned int i; float f; } v; v.i = ((unsigned int)u) << 16; return v.f;
}
static __device__ __forceinline__ ushort_t f2bf(float f) {
    union { float f; unsigned int i; } v; v.f = f;
    unsigned int x = v.i;
    x += 0x7fffu + ((x >> 16) & 1u);   // RNE
    return (ushort_t)(x >> 16);
}
// flag-aware input load: isbf=1 -> bf16 element, isbf=0 -> fp32 element.
// Written as explicit branch (uniform across the grid) so the compiler never
// speculates the wrong-width load.
static __device__ __forceinline__ float ldf(const void* p, long i, unsigned isbf) {
    if (isbf) return bf2f(((const ushort_t*)p)[i]);
    return ((const float*)p)[i];
}
static __device__ __forceinline__ short8 ldfrag(const ushort_t* p) {
    return *reinterpret_cast<const short8*>(p);
}
static __device__ __forceinline__ floatx4 mfma(short8 a, short8 b, floatx4 c) {
    return __builtin_amdgcn_mfma_f32_16x16x32_bf16(a, b, c, 0, 0, 0);
}
static __device__ __forceinline__ float sigmoidf(float x) {
    x = fminf(fmaxf(x, -30.f), 30.f);
    return 1.f / (1.f + __expf(-x));
}
static __device__ __forceinline__ float tanh_f(float x) {
    x = fminf(fmaxf(x, -15.f), 15.f);
    float e = __expf(2.f * x);
    return (e - 1.f) / (e + 1.f);
}
static __device__ __forceinline__ void store_hl(ushort_t* hi_p, ushort_t* lo_p, float v) {
    ushort_t hi = f2bf(v);
    *hi_p = hi;
    *lo_p = f2bf(v - bf2f(hi));
}

// ---------------- dtype detect: bf16 vs fp32 ----------------
__global__ void k_detect(const unsigned* __restrict__ enc, unsigned* __restrict__ flag)
{
    __shared__ int cnt;
    if (threadIdx.x == 0) cnt = 0;
    __syncthreads();
    unsigned w = enc[threadIdx.x];
    unsigned ef = (w >> 7) & 0xFFu;      // exponent field of low half viewed as bf16
    if (ef >= 0x70u && ef <= 0x81u) atomicAdd(&cnt, 1);
    __syncthreads();
    if (threadIdx.x == 0) flag[0] = (cnt >= 200) ? 1u : 0u;
}

// ---------------- prep: pack/pad/transpose/convert inputs ----------------
__global__ void k_prep(const void* __restrict__ eh, const void* __restrict__ Watt,
                       const void* __restrict__ Wwatt, const void* __restrict__ Wih,
                       const void* __restrict__ Wout, const void* __restrict__ pp,
                       const void* __restrict__ Whh, const void* __restrict__ Wed,
                       ushort_t* __restrict__ ehcat, ushort_t* __restrict__ wattT,
                       ushort_t* __restrict__ wwattT, ushort_t* __restrict__ wih_p,
                       ushort_t* __restrict__ wout_p, ushort_t* __restrict__ pp_pad,
                       ushort_t* __restrict__ pose_pad, ushort_t* __restrict__ Wcomb,
                       ushort_t* __restrict__ whh_bf, ushort_t* __restrict__ wed_bf,
                       const unsigned* __restrict__ flag)
{
    unsigned isbf = flag[0];
    long idx = (long)blockIdx.x * 256 + threadIdx.x;
    const long n1 = BB * EE;             // 65536
    const long n2 = (long)HH * EE;       // 1048576 wattT
    const long n3 = (long)256 * HH;      // 262144  wwattT
    const long n4 = (long)3 * HH * KP;   // 491520  wih_p
    const long n5 = (long)NOP * 3 * HH;  // 442368  wout_p
    const long n6 = (long)PLP * BB * KP; // 327680  pp_pad
    const long n7 = (long)BB * KP;       // 10240   pose_pad
    const long n8 = (long)NOP * 1024;    // 147456  Wcomb cols 0..1023
    const long n9 = (long)3 * HH * HH;   // 3145728 whh_bf
    const long n10 = (long)HH * EE;      // 1048576 wed_bf
    if (idx < n1) {
        int b = (int)(idx >> 10), r = (int)(idx & 1023);
        int c = r >> 9, j = r & 511;
        ehcat[idx] = f2bf(ldf(eh, (long)(c * BB + b) * 512 + j, isbf));
        return;
    }
    idx -= n1;
    if (idx < n2) {    // wattT[e][j] = Watt[j][e]
        long e = idx >> 10, j = idx & 1023;
        wattT[idx] = f2bf(ldf(Watt, j * 1024 + e, isbf)); return;
    }
    idx -= n2;
    if (idx < n3) {    // wwattT[e][j] = (e<200) ? Wwatt[j][e] : 0
        long e = idx >> 10, j = idx & 1023;
        wwattT[idx] = (e < 200) ? f2bf(ldf(Wwatt, j * 200 + e, isbf)) : (ushort_t)0; return;
    }
    idx -= n3;
    if (idx < n4) {
        long row = idx / KP, k = idx % KP;
        wih_p[idx] = (k < OO) ? f2bf(ldf(Wih, row * OO + k, isbf)) : (ushort_t)0; return;
    }
    idx -= n4;
    if (idx < n5) {
        long row = idx / (3 * HH), k = idx % (3 * HH);
        wout_p[idx] = (row < OO) ? f2bf(ldf(Wout, row * (3 * HH) + k, isbf)) : (ushort_t)0; return;
    }
    idx -= n5;
    if (idx < n6) {
        long t = idx / (BB * KP); long rem = idx % (BB * KP);
        long b = rem / KP, k = rem % KP;
        pp_pad[idx] = (k < OO) ? f2bf(ldf(pp, (t * BB + b) * OO + k, isbf)) : (ushort_t)0; return;
    }
    idx -= n6;
    if (idx < n7) { pose_pad[idx] = 0; return; }
    idx -= n7;
    if (idx < n8) {    // Wcomb[o][j] = W_out[o][j] for j<1024 (rows >= OO zero)
        long o = idx >> 10, j = idx & 1023;
        Wcomb[o * KC + j] = (o < OO) ? f2bf(ldf(Wout, o * (3 * HH) + j, isbf)) : (ushort_t)0; return;
    }
    idx -= n8;
    if (idx < n9) { whh_bf[idx] = f2bf(ldf(Whh, idx, isbf)); return; }
    idx -= n9;
    if (idx < n10) { wed_bf[idx] = f2bf(ldf(Wed, idx, isbf)); return; }
}

// ---------------- generic MFMA GEMM: out[M][N] = (A (+ Alo)) [M][K] @ Bw[N][K]^T + bias ----------------
__global__ void __launch_bounds__(256) k_gemm(
    const ushort_t* __restrict__ A, const ushort_t* __restrict__ Alo, int lda,
    const ushort_t* __restrict__ Bw, int ldb,
    const void* __restrict__ biasRaw,
    float* __restrict__ outF, ushort_t* __restrict__ outB,
    ushort_t* __restrict__ outHi, ushort_t* __restrict__ outLo,
    int ldo, int M, int N, int K, int ncap, const unsigned* __restrict__ flag)
{
    unsigned isbf = flag[0];
    int lane = threadIdx.x & 63;
    int wid = (blockIdx.x << 2) + (threadIdx.x >> 6);
    int ng = N >> 6;
    int mt = wid / ng, g = wid % ng;
    if (mt * 16 >= M) return;
    int col = lane & 15, quad = lane >> 4;
    const ushort_t* ap = A + (size_t)(mt * 16 + col) * lda + quad * 8;
    const ushort_t* alp = Alo ? (Alo + (size_t)(mt * 16 + col) * lda + quad * 8) : (const ushort_t*)0;
    const ushort_t* bp = Bw + (size_t)((g << 6) + col) * ldb + quad * 8;
    floatx4 ac0 = {0.f, 0.f, 0.f, 0.f}, ac1 = ac0, ac2 = ac0, ac3 = ac0;
    if (alp) {
        for (int k = 0; k < K; k += 32) {
            short8 a = ldfrag(ap + k), al = ldfrag(alp + k);
            short8 f0 = ldfrag(bp + k);
            short8 f1 = ldfrag(bp + (size_t)16 * ldb + k);
            short8 f2 = ldfrag(bp + (size_t)32 * ldb + k);
            short8 f3 = ldfrag(bp + (size_t)48 * ldb + k);
            ac0 = mfma(a, f0, ac0); ac0 = mfma(al, f0, ac0);
            ac1 = mfma(a, f1, ac1); ac1 = mfma(al, f1, ac1);
            ac2 = mfma(a, f2, ac2); ac2 = mfma(al, f2, ac2);
            ac3 = mfma(a, f3, ac3); ac3 = mfma(al, f3, ac3);
        }
    } else {
        for (int k = 0; k < K; k += 32) {
            short8 a = ldfrag(ap + k);
            ac0 = mfma(a, ldfrag(bp + k), ac0);
            ac1 = mfma(a, ldfrag(bp + (size_t)16 * ldb + k), ac1);
            ac2 = mfma(a, ldfrag(bp + (size_t)32 * ldb + k), ac2);
            ac3 = mfma(a, ldfrag(bp + (size_t)48 * ldb + k), ac3);
        }
    }
    int m0 = mt * 16 + quad * 4;
    #pragma unroll
    for (int tIdx = 0; tIdx < 4; ++tIdx) {
        floatx4 ac = (tIdx == 0) ? ac0 : (tIdx == 1) ? ac1 : (tIdx == 2) ? ac2 : ac3;
        int n = (g << 6) + tIdx * 16 + col;
        if (n >= ncap) continue;
        float bv = biasRaw ? ldf(biasRaw, n, isbf) : 0.f;
        #pragma unroll
        for (int r = 0; r < 4; ++r) {
            float v = ac[r] + bv;
            size_t o = (size_t)(m0 + r) * ldo + n;
            if (outF) outF[o] = v;
            if (outB) outB[o] = f2bf(v);
            if (outHi) {
                ushort_t hi = f2bf(v);
                outHi[o] = hi;
                outLo[o] = f2bf(v - bf2f(hi));
            }
        }
    }
}

// ---------------- bcomb = b_out + Wout2 @ b_att + Wout3 @ b_watt ----------------
__global__ void k_bcomb(const ushort_t* __restrict__ wout_p, const void* __restrict__ b_out,
                        const void* __restrict__ b_att, const void* __restrict__ b_watt,
                        float* __restrict__ bcomb, const unsigned* __restrict__ flag)
{
    unsigned isbf = flag[0];
    int o = threadIdx.x;
    if (o >= NOP) return;
    float s = (o < OO) ? ldf(b_out, o, isbf) : 0.f;
    const ushort_t* r2 = wout_p + (size_t)o * (3 * HH) + 1024;
    const ushort_t* r3 = wout_p + (size_t)o * (3 * HH) + 2048;
    for (int j = 0; j < HH; ++j) {
        s += bf2f(r2[j]) * ldf(b_att, j, isbf);
        s += bf2f(r3[j]) * ldf(b_watt, j, isbf);
    }
    bcomb[o] = s;
}

// ---------------- fused GRU step ----------------
__global__ void __launch_bounds__(256) k_gru(
    const float* __restrict__ hF_src, const ushort_t* __restrict__ hhi, const ushort_t* __restrict__ hlo,
    float* __restrict__ hF_dst, ushort_t* __restrict__ hhi_d, ushort_t* __restrict__ hlo_d,
    const ushort_t* __restrict__ poseA,
    const ushort_t* __restrict__ Whh, const ushort_t* __restrict__ wih_p,
    const void* __restrict__ b_ih, const void* __restrict__ b_hh,
    ushort_t* __restrict__ cxh, ushort_t* __restrict__ cxl,
    const unsigned* __restrict__ flag)
{
    unsigned isbf = flag[0];
    int lane = threadIdx.x & 63, wv = threadIdx.x >> 6;
    int jt = blockIdx.x;
    int col = lane & 15, quad = lane >> 4;
    const ushort_t* ah = hhi + (size_t)(wv * 16 + col) * HH + quad * 8;
    const ushort_t* al = hlo + (size_t)(wv * 16 + col) * HH + quad * 8;
    const ushort_t* b0 = Whh + (size_t)(jt * 16 + col) * HH + quad * 8;
    const ushort_t* b1 = b0 + (size_t)HH * HH;
    const ushort_t* b2 = b0 + (size_t)2 * HH * HH;
    floatx4 aR = {0.f, 0.f, 0.f, 0.f}, aZ = aR, aNi = aR, aNh = aR;
    for (int k = 0; k < HH; k += 32) {
        short8 fr0 = ldfrag(b0 + k), fr1 = ldfrag(b1 + k), fr2 = ldfrag(b2 + k);
        short8 xh = ldfrag(ah + k), xl = ldfrag(al + k);
        aR = mfma(xh, fr0, aR);  aR = mfma(xl, fr0, aR);
        aZ = mfma(xh, fr1, aZ);  aZ = mfma(xl, fr1, aZ);
        aNh = mfma(xh, fr2, aNh); aNh = mfma(xl, fr2, aNh);
    }
    const ushort_t* app = poseA + (size_t)(wv * 16 + col) * KP + quad * 8;
    const ushort_t* c0 = wih_p + (size_t)(jt * 16 + col) * KP + quad * 8;
    const ushort_t* c1 = c0 + (size_t)HH * KP;
    const ushort_t* c2 = c0 + (size_t)2 * HH * KP;
    for (int k = 0; k < KP; k += 32) {
        short8 xp = ldfrag(app + k);
        aR = mfma(xp, ldfrag(c0 + k), aR);
        aZ = mfma(xp, ldfrag(c1 + k), aZ);
        aNi = mfma(xp, ldfrag(c2 + k), aNi);
    }
    int j = jt * 16 + col;
    float bir = ldf(b_ih, j, isbf),          bhr = ldf(b_hh, j, isbf);
    float biz = ldf(b_ih, HH + j, isbf),     bhz = ldf(b_hh, HH + j, isbf);
    float bin = ldf(b_ih, 2 * HH + j, isbf), bhn = ldf(b_hh, 2 * HH + j, isbf);
    #pragma unroll
    for (int r = 0; r < 4; ++r) {
        int b = wv * 16 + quad * 4 + r;
        float hold = hF_src[(size_t)b * HH + j];
        float rg = sigmoidf(aR[r] + bir + bhr);
        float zg = sigmoidf(aZ[r] + biz + bhz);
        float ng = tanh_f(aNi[r] + bin + rg * (aNh[r] + bhn));
        float hn = (1.f - zg) * ng + zg * hold;
        hF_dst[(size_t)b * HH + j] = hn;
        ushort_t hi = f2bf(hn);
        ushort_t lo = f2bf(hn - bf2f(hi));
        hhi_d[(size_t)b * HH + j] = hi;
        hlo_d[(size_t)b * HH + j] = lo;
        if (cxh) { cxh[(size_t)b * KC + j] = hi; cxl[(size_t)b * KC + j] = lo; }
    }
}

// ---------------- fused scores + softmax + weighted sums, one wg per batch ----------------
__global__ void __launch_bounds__(256) k_scorectx(
    const float* __restrict__ gcat, const void* __restrict__ enc,
    const void* __restrict__ words,
    ushort_t* __restrict__ cxh, ushort_t* __restrict__ cxl,
    const unsigned* __restrict__ flag)
{
    __shared__ float gs[1280];
    __shared__ float sc[192];
    __shared__ float wts[192];
    unsigned isbf = flag[0];
    int b = blockIdx.x;
    int tid = threadIdx.x, lane = tid & 63, wv = tid >> 6;
    #pragma unroll
    for (int i = 0; i < 5; ++i) gs[tid + 256 * i] = gcat[(size_t)b * 1280 + tid + 256 * i];
    __syncthreads();
    for (int idx = wv; idx < 192; idx += 4) {
        float s = 0.f;
        if (idx < 128) {
            long base = (long)(idx * BB + b) << 10;
            #pragma unroll
            for (int jj = 0; jj < 16; ++jj) {
                int k = lane + (jj << 6);
                s += ldf(enc, base + k, isbf) * gs[k];
            }
        } else {
            long base = (long)((idx - 128) * BB + b) * 200;
            #pragma unroll
            for (int jj = 0; jj < 4; ++jj) {
                int k = lane + (jj << 6);
                if (k < 200) s += ldf(words, base + k, isbf) * gs[1024 + k];
            }
        }
        #pragma unroll
        for (int m = 1; m < 64; m <<= 1) s += __shfl_xor(s, m);
        if (lane == 0) sc[idx] = s;
    }
    __syncthreads();
    if (wv == 0) {
        float a = sc[lane], c = sc[lane + 64];
        float mx = fmaxf(a, c);
        #pragma unroll
        for (int m = 1; m < 64; m <<= 1) mx = fmaxf(mx, __shfl_xor(mx, m));
        float e0 = __expf(a - mx), e1 = __expf(c - mx);
        float sm = e0 + e1;
        #pragma unroll
        for (int m = 1; m < 64; m <<= 1) sm += __shfl_xor(sm, m);
        float inv = 1.f / sm;
        wts[lane] = e0 * inv; wts[lane + 64] = e1 * inv;
    } else if (wv == 1) {
        float a = sc[128 + lane];
        float mx = a;
        #pragma unroll
        for (int m = 1; m < 64; m <<= 1) mx = fmaxf(mx, __shfl_xor(mx, m));
        float e0 = __expf(a - mx);
        float sm = e0;
        #pragma unroll
        for (int m = 1; m < 64; m <<= 1) sm += __shfl_xor(sm, m);
        wts[128 + lane] = e0 / sm;
    }
    __syncthreads();
    // esum = sum_s wts[s] * enc[s][b][:]  -> catx cols 1024..2047
    float a0 = 0.f, a1 = 0.f, a2 = 0.f, a3 = 0.f;
    for (int s = 0; s < SS; ++s) {
        float w = wts[s];
        long base = ((long)(s * BB + b) << 10) + tid;
        a0 += w * ldf(enc, base, isbf);       a1 += w * ldf(enc, base + 256, isbf);
        a2 += w * ldf(enc, base + 512, isbf); a3 += w * ldf(enc, base + 768, isbf);
    }
    size_t cb = (size_t)b * KC + 1024;
    store_hl(cxh + cb + tid, cxl + cb + tid, a0);
    store_hl(cxh + cb + tid + 256, cxl + cb + tid + 256, a1);
    store_hl(cxh + cb + tid + 512, cxl + cb + tid + 512, a2);
    store_hl(cxh + cb + tid + 768, cxl + cb + tid + 768, a3);
    // wsum -> catx cols 2048..2271
    if (tid < 224) {
        float s224 = 0.f;
        if (tid < 200) {
            for (int s = 0; s < WLW; ++s)
                s224 += wts[128 + s] * ldf(words, (long)(s * BB + b) * 200 + tid, isbf);
        }
        size_t cw = (size_t)b * KC + 2048 + tid;
        store_hl(cxh + cw, cxl + cw, s224);
    }
}

// ---------------- pose = catx @ Wcomb^T + bcomb ----------------
__global__ void __launch_bounds__(256) k_pose(
    const ushort_t* __restrict__ cxh, const ushort_t* __restrict__ cxl,
    const ushort_t* __restrict__ Wcomb, const float* __restrict__ bcomb,
    void* __restrict__ out, ushort_t* __restrict__ pose_pad, int t,
    const unsigned* __restrict__ flag)
{
    unsigned isbf = flag[0];
    int lane = threadIdx.x & 63;
    int wid = blockIdx.x * 4 + (threadIdx.x >> 6);   // 0..35
    int mt = wid / 9, nt = wid % 9;
    int col = lane & 15, quad = lane >> 4;
    const ushort_t* ah = cxh + (size_t)(mt * 16 + col) * KC + quad * 8;
    const ushort_t* al = cxl + (size_t)(mt * 16 + col) * KC + quad * 8;
    const ushort_t* bp = Wcomb + (size_t)(nt * 16 + col) * KC + quad * 8;
    floatx4 ac = {0.f, 0.f, 0.f, 0.f};
    for (int k = 0; k < KC; k += 32) {
        short8 bf = ldfrag(bp + k);
        ac = mfma(ldfrag(ah + k), bf, ac);
        ac = mfma(ldfrag(al + k), bf, ac);
    }
    int o = nt * 16 + col;
    float bv = bcomb[o];
    #pragma unroll
    for (int r = 0; r < 4; ++r) {
        int bidx = mt * 16 + quad * 4 + r;
        float v = ac[r] + bv;
        if (o < OO) {
            size_t oi = ((size_t)t * BB + bidx) * OO + o;
            if (isbf) ((ushort_t*)out)[oi] = f2bf(v);
            else      ((float*)out)[oi] = v;
        }
        pose_pad[(size_t)bidx * KP + o] = (o < OO) ? f2bf(v) : (ushort_t)0;
    }
}

extern "C" void kernel_launch(void* const* d_in, const int* in_sizes, int n_in,
                              void* d_out, int out_size, void* d_ws, size_t ws_size,
                              hipStream_t stream)
{
    (void)in_sizes; (void)n_in; (void)out_size; (void)ws_size;
    const void* enc_states = d_in[0];
    const void* enc_hidden = d_in[1];
    const void* prev_poses = d_in[2];
    const void* words      = d_in[3];
    // d_in[4] = real_poses_len (fixed 100)
    const void* W_ed  = d_in[5];
    const void* b_ed  = d_in[6];
    const void* W_att = d_in[7];
    const void* b_att = d_in[8];
    const void* W_watt = d_in[9];
    const void* b_watt = d_in[10];
    const void* W_ih  = d_in[11];
    const void* W_hh  = d_in[12];
    const void* b_ih  = d_in[13];
    const void* b_hh  = d_in[14];
    const void* W_out = d_in[15];
    const void* b_out = d_in[16];

    char* base = (char*)d_ws;
    size_t off = 0;
    auto alloc = [&](size_t bytes) -> char* {
        char* p = base + off;
        off = (off + bytes + 255) & ~(size_t)255;
        return p;
    };
    unsigned* flag     = (unsigned*)alloc(256);
    ushort_t* ehcat    = (ushort_t*)alloc((size_t)BB * EE * 2);
    ushort_t* wattT    = (ushort_t*)alloc((size_t)HH * EE * 2);          // 2 MB
    ushort_t* wwattT   = (ushort_t*)alloc((size_t)256 * HH * 2);         // contiguous after wattT
    ushort_t* wih_p    = (ushort_t*)alloc((size_t)3 * HH * KP * 2);
    ushort_t* wout_p   = (ushort_t*)alloc((size_t)NOP * 3 * HH * 2);
    ushort_t* pp_pad   = (ushort_t*)alloc((size_t)PLP * BB * KP * 2);
    ushort_t* pose_pad = (ushort_t*)alloc((size_t)BB * KP * 2);
    ushort_t* Wcomb    = (ushort_t*)alloc((size_t)NOP * KC * 2);
    float*    bcomb    = (float*)alloc((size_t)NOP * 4);
    ushort_t* whh_bf   = (ushort_t*)alloc((size_t)3 * HH * HH * 2);      // 6.3 MB
    ushort_t* wed_bf   = (ushort_t*)alloc((size_t)HH * EE * 2);          // 2 MB
    float*    hF0      = (float*)alloc((size_t)BB * HH * 4);
    float*    hF1      = (float*)alloc((size_t)BB * HH * 4);
    ushort_t* hhi0     = (ushort_t*)alloc((size_t)BB * HH * 2);
    ushort_t* hhi1     = (ushort_t*)alloc((size_t)BB * HH * 2);
    ushort_t* hlo0     = (ushort_t*)alloc((size_t)BB * HH * 2);
    ushort_t* hlo1     = (ushort_t*)alloc((size_t)BB * HH * 2);
    float*    gcat     = (float*)alloc((size_t)BB * 1280 * 4);
    ushort_t* cxh      = (ushort_t*)alloc((size_t)BB * KC * 2);
    ushort_t* cxl      = (ushort_t*)alloc((size_t)BB * KC * 2);
    // total ~17 MB

    float*    hF[2]  = {hF0, hF1};
    ushort_t* hhi[2] = {hhi0, hhi1};
    ushort_t* hlo[2] = {hlo0, hlo1};

    k_detect<<<1, 256, 0, stream>>>((const unsigned*)enc_states, flag);

    k_prep<<<27304, 256, 0, stream>>>(enc_hidden, W_att, W_watt, W_ih, W_out, prev_poses,
                                      W_hh, W_ed,
                                      ehcat, wattT, wwattT, wih_p, wout_p, pp_pad, pose_pad,
                                      Wcomb, whh_bf, wed_bf, flag);

    // h0 = ehcat @ W_ed^T + b_ed    (M=64, N=1024, K=1024)
    k_gemm<<<16, 256, 0, stream>>>(ehcat, nullptr, EE, wed_bf, EE, b_ed,
                                   hF[0], nullptr, hhi[0], hlo[0], HH, BB, HH, EE, HH, flag);
    // Wcomb cols 1024..2047 = wout2 @ wattT^T   (M=144, N=1024, K=1024)
    k_gemm<<<36, 256, 0, stream>>>(wout_p + 1024, nullptr, 3 * HH, wattT, HH, nullptr,
                                   nullptr, Wcomb + 1024, nullptr, nullptr, KC, NOP, HH, HH, HH, flag);
    // Wcomb cols 2048..2271 = wout3 @ wwattT^T  (M=144, N=256 capped 224, K=1024)
    k_gemm<<<9, 256, 0, stream>>>(wout_p + 2048, nullptr, 3 * HH, wwattT, HH, nullptr,
                                  nullptr, Wcomb + 2048, nullptr, nullptr, KC, NOP, 256, HH, 224, flag);
    k_bcomb<<<1, 256, 0, stream>>>(wout_p, b_out, b_att, b_watt, bcomb, flag);

    int cur = 0;
    for (int t = 0; t < PLP; ++t) {
        k_gru<<<64, 256, 0, stream>>>(hF[cur], hhi[cur], hlo[cur],
                                      hF[1 - cur], hhi[1 - cur], hlo[1 - cur],
                                      pp_pad + (size_t)t * BB * KP,
                                      whh_bf, wih_p, b_ih, b_hh, nullptr, nullptr, flag);
        cur ^= 1;
    }
    for (int t = 0; t < TT; ++t) {
        const ushort_t* poseA = (t == 0) ? (pp_pad + (size_t)(PLP - 1) * BB * KP) : pose_pad;
        k_gru<<<64, 256, 0, stream>>>(hF[cur], hhi[cur], hlo[cur],
                                      hF[1 - cur], hhi[1 - cur], hlo[1 - cur],
                                      poseA, whh_bf, wih_p, b_ih, b_hh, cxh, cxl, flag);
        cur ^= 1;
        // gcat = h @ [wattT | wwattT]^T   (M=64, N=1280, K=1024), fp32 out
        k_gemm<<<20, 256, 0, stream>>>(hhi[cur], hlo[cur], HH, wattT, HH, nullptr,
                                       gcat, nullptr, nullptr, nullptr, 1280, BB, 1280, HH, 1280, flag);
        k_scorectx<<<64, 256, 0, stream>>>(gcat, enc_states, words, cxh, cxl, flag);
        k_pose<<<9, 256, 0, stream>>>(cxh, cxl, Wcomb, bcomb, d_out, pose_pad, t, flag);
    }
}